// Round 3
// baseline (810.237 us; speedup 1.0000x reference)
//
#include <hip/hip_runtime.h>
#include <math.h>

#define NPTS 262144
#define KCL  256
#define DDIM 64
#define RPW  16                    // rows per wave
#define WPB  4                     // waves per block
#define RPB  (RPW * WPB)           // 64 rows per block
#define NBLK_MAIN (NPTS / RPB)     // 4096
#define NPART (NPTS / RPW)         // 16384 partials
#define ALPHA_DP 1.0f

typedef float f32x4 __attribute__((ext_vector_type(4)));

// ws layout (float offsets):
#define OFF_WB   (DDIM * KCL)
#define OFF_BASE (2 * DDIM * KCL)
#define OFF_KL   (2 * DDIM * KCL + KCL)
#define OFF_PART (2 * DDIM * KCL + KCL + 1)

__device__ __forceinline__ float digamma_f(float x) {
  float r = 0.0f;
  while (x < 6.0f) { r -= 1.0f / x; x += 1.0f; }
  float inv  = 1.0f / x;
  float inv2 = inv * inv;
  return r + logf(x) - 0.5f * inv
       - inv2 * (0.083333333333333333f
         - inv2 * (0.008333333333333333f
           - inv2 * 0.003968253968253968f));
}

__global__ void dpmm_prep(const float* __restrict__ u, const float* __restrict__ v,
                          const float* __restrict__ tau, const float* __restrict__ c,
                          const float* __restrict__ n, const float* __restrict__ B,
                          const float* __restrict__ tau0, const float* __restrict__ c0,
                          const float* __restrict__ n0, const float* __restrict__ B0,
                          float* __restrict__ ws) {
  __shared__ float eb_s[KCL], e1b_s[KCL], elogpi_s[KCL];
  __shared__ double kl_s[KCL];
  const int k = threadIdx.x;

  float uk = u[k], vk = v[k];
  float dig_sum = digamma_f(uk + vk);
  float eb  = digamma_f(uk) - dig_sum;
  float e1b = digamma_f(vk) - dig_sum;
  eb_s[k] = eb; e1b_s[k] = e1b;
  __syncthreads();
  if (k == 0) {
    float run = 0.0f;
    for (int j = 0; j < KCL; ++j) { elogpi_s[j] = eb_s[j] + run; run += e1b_s[j]; }
  }
  __syncthreads();

  float nk = n[k], ck = c[k], n0k = n0[k], c0k = c0[k];
  float a = 0.5f * nk, a0 = 0.5f * n0k;
  float dga  = digamma_f(a);
  float lga  = lgammaf(a);
  float lga0 = lgammaf(a0);

  float  sumNegLogB = 0.0f, sumElamTau2 = 0.0f;
  double klg = 0.0, knq = 0.0;
  for (int d = 0; d < DDIM; ++d) {
    float Bkd  = B[k * DDIM + d];
    float tkd  = tau[k * DDIM + d];
    float B0kd = B0[k * DDIM + d];
    float t0kd = tau0[k * DDIM + d];
    float Elam = nk / Bkd;
    ws[d * KCL + k]          = -0.5f * Elam;   // WA_t
    ws[OFF_WB + d * KCL + k] = Elam * tkd;     // WB_t
    sumNegLogB  -= logf(Bkd);
    sumElamTau2 += Elam * tkd * tkd;
    float b = 0.5f * Bkd, b0 = 0.5f * B0kd;
    klg += (double)((a - a0) * dga - lga + lga0
                    + a0 * (logf(b) - logf(b0)) + a * (b0 - b) / b);
    float dt = tkd - t0kd;
    knq += (double)(Elam * dt * dt);
  }
  float sumEloglam = (float)DDIM * (dga + 0.6931471805599453f) + sumNegLogB;
  ws[OFF_BASE + k] = elogpi_s[k]
      + 0.5f * (sumEloglam - (float)DDIM * 1.8378770664093453f
                - (float)DDIM / ck - sumElamTau2);

  float klb = lgammaf(uk + vk) - lgammaf(uk) - lgammaf(vk)
            - (lgammaf(1.0f + ALPHA_DP) - lgammaf(ALPHA_DP))
            + (uk - 1.0f) * eb + (vk - ALPHA_DP) * e1b;
  float kln = 0.5f * (float)DDIM * (c0k / ck - 1.0f + logf(ck / c0k))
            + 0.5f * c0k * (float)knq;
  kl_s[k] = (double)klb + klg + (double)kln;
  __syncthreads();
  if (k == 0) {
    double tot = 0.0;
    for (int j = 0; j < KCL; ++j) tot += kl_s[j];
    ws[OFF_KL] = (float)tot;
  }
}

__global__ __launch_bounds__(256, 4) void dpmm_main(
    const float* __restrict__ x,
    const float* __restrict__ WA, const float* __restrict__ WB,
    const float* __restrict__ base,
    float* __restrict__ pi, float* __restrict__ partial) {
  const int t = threadIdx.x & 63;        // lane
  const int w = threadIdx.x >> 6;        // wave 0..3
  const long row0 = (long)blockIdx.x * RPB + (long)w * RPW;

  // wave-private region: no cross-wave deps -> no __syncthreads needed
  __shared__ float2 xx[WPB][RPW][DDIM];  // 32 KB

  #pragma unroll
  for (int i = 0; i < RPW; ++i) {
    float xv = x[(row0 + i) * DDIM + t];  // coalesced 256B per wave
    xx[w][i][t] = make_float2(xv, xv * xv);
  }

  // lane t owns k = 4t .. 4t+3  -> float4 weight loads / pi stores
  float acc[4][RPW];
  {
    float4 bb = *reinterpret_cast<const float4*>(&base[4 * t]);
    #pragma unroll
    for (int i = 0; i < RPW; ++i) {
      acc[0][i] = bb.x; acc[1][i] = bb.y; acc[2][i] = bb.z; acc[3][i] = bb.w;
    }
  }

  #pragma unroll 4
  for (int d = 0; d < DDIM; ++d) {
    float4 wa = *reinterpret_cast<const float4*>(&WA[d * KCL + 4 * t]);
    float4 wb = *reinterpret_cast<const float4*>(&WB[d * KCL + 4 * t]);
    #pragma unroll
    for (int i = 0; i < RPW; ++i) {
      float2 vv = xx[w][i][d];             // broadcast read
      acc[0][i] = fmaf(wa.x, vv.y, fmaf(wb.x, vv.x, acc[0][i]));
      acc[1][i] = fmaf(wa.y, vv.y, fmaf(wb.y, vv.x, acc[1][i]));
      acc[2][i] = fmaf(wa.z, vv.y, fmaf(wb.z, vv.x, acc[2][i]));
      acc[3][i] = fmaf(wa.w, vv.y, fmaf(wb.w, vv.x, acc[3][i]));
    }
  }

  float lsum = 0.0f;
  #pragma unroll 1
  for (int i = 0; i < RPW; ++i) {
    float m = fmaxf(fmaxf(acc[0][i], acc[1][i]), fmaxf(acc[2][i], acc[3][i]));
    #pragma unroll
    for (int off = 32; off; off >>= 1) m = fmaxf(m, __shfl_xor(m, off, 64));
    float e0 = __expf(acc[0][i] - m);
    float e1 = __expf(acc[1][i] - m);
    float e2 = __expf(acc[2][i] - m);
    float e3 = __expf(acc[3][i] - m);
    float s = e0 + e1 + e2 + e3;
    #pragma unroll
    for (int off = 32; off; off >>= 1) s += __shfl_xor(s, off, 64);
    float rs = 1.0f / s;
    f32x4 pv = { e0 * rs, e1 * rs, e2 * rs, e3 * rs };
    __builtin_nontemporal_store(pv,
        reinterpret_cast<f32x4*>(&pi[(size_t)(row0 + i) * KCL + 4 * t]));
    lsum += m + __logf(s);
  }
  if (t == 0) partial[blockIdx.x * WPB + w] = lsum;
}

__global__ void dpmm_fin(const float* __restrict__ partial,
                         const float* __restrict__ kl,
                         float* __restrict__ out_elbo) {
  __shared__ double red[256];
  const int t = threadIdx.x;
  double s = 0.0;
  for (int i = t; i < NPART; i += 256) s += (double)partial[i];
  red[t] = s;
  __syncthreads();
  for (int off = 128; off; off >>= 1) {
    if (t < off) red[t] += red[t + off];
    __syncthreads();
  }
  if (t == 0) out_elbo[0] = (float)(red[0] - (double)kl[0]);
}

extern "C" void kernel_launch(void* const* d_in, const int* in_sizes, int n_in,
                              void* d_out, int out_size, void* d_ws, size_t ws_size,
                              hipStream_t stream) {
  const float* x    = (const float*)d_in[0];
  const float* u    = (const float*)d_in[1];
  const float* v    = (const float*)d_in[2];
  const float* tau  = (const float*)d_in[3];
  const float* c    = (const float*)d_in[4];
  const float* n    = (const float*)d_in[5];
  const float* B    = (const float*)d_in[6];
  const float* tau0 = (const float*)d_in[7];
  const float* c0   = (const float*)d_in[8];
  const float* n0   = (const float*)d_in[9];
  const float* B0   = (const float*)d_in[10];

  float* out = (float*)d_out;
  float* ws  = (float*)d_ws;

  dpmm_prep<<<1, KCL, 0, stream>>>(u, v, tau, c, n, B, tau0, c0, n0, B0, ws);

  const float* WA   = ws;
  const float* WB   = ws + OFF_WB;
  const float* base = ws + OFF_BASE;
  const float* kl   = ws + OFF_KL;
  float* partial    = ws + OFF_PART;

  dpmm_main<<<NBLK_MAIN, 256, 0, stream>>>(x, WA, WB, base, out, partial);
  dpmm_fin<<<1, 256, 0, stream>>>(partial, kl, out + (size_t)NPTS * KCL);
}

// Round 4
// 449.656 us; speedup vs baseline: 1.8019x; 1.8019x over previous
//
#include <hip/hip_runtime.h>
#include <math.h>

#define NPTS 262144
#define KCL  256
#define DDIM 64
#define RPW  16                    // rows per wave
#define WPB  4                     // waves per block
#define RPB  (RPW * WPB)           // 64 rows per block
#define NBLK_MAIN (NPTS / RPB)     // 4096
#define NPART (NPTS / RPW)         // 16384 partials
#define ALPHA_DP 1.0f

typedef float f32x4 __attribute__((ext_vector_type(4)));

// ws layout (float offsets):
#define OFF_WB   (DDIM * KCL)
#define OFF_BASE (2 * DDIM * KCL)
#define OFF_KL   (2 * DDIM * KCL + KCL)
#define OFF_PART (2 * DDIM * KCL + KCL + 1)

__device__ __forceinline__ float digamma_f(float x) {
  float r = 0.0f;
  while (x < 6.0f) { r -= 1.0f / x; x += 1.0f; }
  float inv  = 1.0f / x;
  float inv2 = inv * inv;
  return r + logf(x) - 0.5f * inv
       - inv2 * (0.083333333333333333f
         - inv2 * (0.008333333333333333f
           - inv2 * 0.003968253968253968f));
}

__global__ void dpmm_prep(const float* __restrict__ u, const float* __restrict__ v,
                          const float* __restrict__ tau, const float* __restrict__ c,
                          const float* __restrict__ n, const float* __restrict__ B,
                          const float* __restrict__ tau0, const float* __restrict__ c0,
                          const float* __restrict__ n0, const float* __restrict__ B0,
                          float* __restrict__ ws) {
  __shared__ float eb_s[KCL], e1b_s[KCL], elogpi_s[KCL];
  __shared__ double kl_s[KCL];
  const int k = threadIdx.x;

  float uk = u[k], vk = v[k];
  float dig_sum = digamma_f(uk + vk);
  float eb  = digamma_f(uk) - dig_sum;
  float e1b = digamma_f(vk) - dig_sum;
  eb_s[k] = eb; e1b_s[k] = e1b;
  __syncthreads();
  if (k == 0) {
    float run = 0.0f;
    for (int j = 0; j < KCL; ++j) { elogpi_s[j] = eb_s[j] + run; run += e1b_s[j]; }
  }
  __syncthreads();

  float nk = n[k], ck = c[k], n0k = n0[k], c0k = c0[k];
  float a = 0.5f * nk, a0 = 0.5f * n0k;
  float dga  = digamma_f(a);
  float lga  = lgammaf(a);
  float lga0 = lgammaf(a0);

  float  sumNegLogB = 0.0f, sumElamTau2 = 0.0f;
  double klg = 0.0, knq = 0.0;
  for (int d = 0; d < DDIM; ++d) {
    float Bkd  = B[k * DDIM + d];
    float tkd  = tau[k * DDIM + d];
    float B0kd = B0[k * DDIM + d];
    float t0kd = tau0[k * DDIM + d];
    float Elam = nk / Bkd;
    ws[d * KCL + k]          = -0.5f * Elam;   // WA_t
    ws[OFF_WB + d * KCL + k] = Elam * tkd;     // WB_t
    sumNegLogB  -= logf(Bkd);
    sumElamTau2 += Elam * tkd * tkd;
    float b = 0.5f * Bkd, b0 = 0.5f * B0kd;
    klg += (double)((a - a0) * dga - lga + lga0
                    + a0 * (logf(b) - logf(b0)) + a * (b0 - b) / b);
    float dt = tkd - t0kd;
    knq += (double)(Elam * dt * dt);
  }
  float sumEloglam = (float)DDIM * (dga + 0.6931471805599453f) + sumNegLogB;
  ws[OFF_BASE + k] = elogpi_s[k]
      + 0.5f * (sumEloglam - (float)DDIM * 1.8378770664093453f
                - (float)DDIM / ck - sumElamTau2);

  float klb = lgammaf(uk + vk) - lgammaf(uk) - lgammaf(vk)
            - (lgammaf(1.0f + ALPHA_DP) - lgammaf(ALPHA_DP))
            + (uk - 1.0f) * eb + (vk - ALPHA_DP) * e1b;
  float kln = 0.5f * (float)DDIM * (c0k / ck - 1.0f + logf(ck / c0k))
            + 0.5f * c0k * (float)knq;
  kl_s[k] = (double)klb + klg + (double)kln;
  __syncthreads();
  if (k == 0) {
    double tot = 0.0;
    for (int j = 0; j < KCL; ++j) tot += kl_s[j];
    ws[OFF_KL] = (float)tot;
  }
}

// NOTE: no min-waves arg — __launch_bounds__(256,4) capped VGPR at 64 and
// spilled acc[4][16] to scratch (R3: WRITE_SIZE 2.6 GB, dur 866us).
__global__ __launch_bounds__(256) void dpmm_main(
    const float* __restrict__ x,
    const float* __restrict__ WA, const float* __restrict__ WB,
    const float* __restrict__ base,
    float* __restrict__ pi, float* __restrict__ partial) {
  const int t = threadIdx.x & 63;        // lane
  const int w = threadIdx.x >> 6;        // wave 0..3
  const long row0 = (long)blockIdx.x * RPB + (long)w * RPW;

  // wave-private region: no cross-wave deps -> no __syncthreads needed
  __shared__ float2 xx[WPB][RPW][DDIM];  // 32 KB

  #pragma unroll
  for (int i = 0; i < RPW; ++i) {
    float xv = x[(row0 + i) * DDIM + t];  // coalesced 256B per wave
    xx[w][i][t] = make_float2(xv, xv * xv);
  }

  // lane t owns k = 4t .. 4t+3  -> float4 weight loads / pi stores
  float acc[4][RPW];
  {
    float4 bb = *reinterpret_cast<const float4*>(&base[4 * t]);
    #pragma unroll
    for (int i = 0; i < RPW; ++i) {
      acc[0][i] = bb.x; acc[1][i] = bb.y; acc[2][i] = bb.z; acc[3][i] = bb.w;
    }
  }

  #pragma unroll 4
  for (int d = 0; d < DDIM; ++d) {
    float4 wa = *reinterpret_cast<const float4*>(&WA[d * KCL + 4 * t]);
    float4 wb = *reinterpret_cast<const float4*>(&WB[d * KCL + 4 * t]);
    #pragma unroll
    for (int i = 0; i < RPW; ++i) {
      float2 vv = xx[w][i][d];             // broadcast read
      acc[0][i] = fmaf(wa.x, vv.y, fmaf(wb.x, vv.x, acc[0][i]));
      acc[1][i] = fmaf(wa.y, vv.y, fmaf(wb.y, vv.x, acc[1][i]));
      acc[2][i] = fmaf(wa.z, vv.y, fmaf(wb.z, vv.x, acc[2][i]));
      acc[3][i] = fmaf(wa.w, vv.y, fmaf(wb.w, vv.x, acc[3][i]));
    }
  }

  float lsum = 0.0f;
  #pragma unroll 1
  for (int i = 0; i < RPW; ++i) {
    float m = fmaxf(fmaxf(acc[0][i], acc[1][i]), fmaxf(acc[2][i], acc[3][i]));
    #pragma unroll
    for (int off = 32; off; off >>= 1) m = fmaxf(m, __shfl_xor(m, off, 64));
    float e0 = __expf(acc[0][i] - m);
    float e1 = __expf(acc[1][i] - m);
    float e2 = __expf(acc[2][i] - m);
    float e3 = __expf(acc[3][i] - m);
    float s = e0 + e1 + e2 + e3;
    #pragma unroll
    for (int off = 32; off; off >>= 1) s += __shfl_xor(s, off, 64);
    float rs = 1.0f / s;
    f32x4 pv = { e0 * rs, e1 * rs, e2 * rs, e3 * rs };
    __builtin_nontemporal_store(pv,
        reinterpret_cast<f32x4*>(&pi[(size_t)(row0 + i) * KCL + 4 * t]));
    lsum += m + __logf(s);
  }
  if (t == 0) partial[blockIdx.x * WPB + w] = lsum;
}

__global__ void dpmm_fin(const float* __restrict__ partial,
                         const float* __restrict__ kl,
                         float* __restrict__ out_elbo) {
  __shared__ double red[256];
  const int t = threadIdx.x;
  double s = 0.0;
  for (int i = t; i < NPART; i += 256) s += (double)partial[i];
  red[t] = s;
  __syncthreads();
  for (int off = 128; off; off >>= 1) {
    if (t < off) red[t] += red[t + off];
    __syncthreads();
  }
  if (t == 0) out_elbo[0] = (float)(red[0] - (double)kl[0]);
}

extern "C" void kernel_launch(void* const* d_in, const int* in_sizes, int n_in,
                              void* d_out, int out_size, void* d_ws, size_t ws_size,
                              hipStream_t stream) {
  const float* x    = (const float*)d_in[0];
  const float* u    = (const float*)d_in[1];
  const float* v    = (const float*)d_in[2];
  const float* tau  = (const float*)d_in[3];
  const float* c    = (const float*)d_in[4];
  const float* n    = (const float*)d_in[5];
  const float* B    = (const float*)d_in[6];
  const float* tau0 = (const float*)d_in[7];
  const float* c0   = (const float*)d_in[8];
  const float* n0   = (const float*)d_in[9];
  const float* B0   = (const float*)d_in[10];

  float* out = (float*)d_out;
  float* ws  = (float*)d_ws;

  dpmm_prep<<<1, KCL, 0, stream>>>(u, v, tau, c, n, B, tau0, c0, n0, B0, ws);

  const float* WA   = ws;
  const float* WB   = ws + OFF_WB;
  const float* base = ws + OFF_BASE;
  const float* kl   = ws + OFF_KL;
  float* partial    = ws + OFF_PART;

  dpmm_main<<<NBLK_MAIN, 256, 0, stream>>>(x, WA, WB, base, out, partial);
  dpmm_fin<<<1, 256, 0, stream>>>(partial, kl, out + (size_t)NPTS * KCL);
}

// Round 5
// 284.897 us; speedup vs baseline: 2.8440x; 1.5783x over previous
//
#include <hip/hip_runtime.h>
#include <math.h>

#define NPTS 262144
#define KCL  256
#define DDIM 64
#define ALPHA_DP 1.0f

#define ROWS_PER_WAVE 32
#define WAVES_PER_BLK 8
#define ROWS_PER_BLK  (ROWS_PER_WAVE * WAVES_PER_BLK)   // 256
#define NBLK_MAIN     (NPTS / ROWS_PER_BLK)             // 1024
#define NPART         (NPTS / ROWS_PER_WAVE)            // 8192

// ws float offsets: [0..32768) Wprep (65536 fp16), base, kl, partials
#define OFF_BASE 32768
#define OFF_KL   33024
#define OFF_PART 33025

typedef _Float16 f16x8 __attribute__((ext_vector_type(8)));
typedef float    f32x4 __attribute__((ext_vector_type(4)));

__device__ __forceinline__ float digamma_f(float x) {
  float r = 0.0f;
  while (x < 6.0f) { r -= 1.0f / x; x += 1.0f; }
  float inv  = 1.0f / x;
  float inv2 = inv * inv;
  return r + logf(x) - 0.5f * inv
       - inv2 * (0.083333333333333333f
         - inv2 * (0.008333333333333333f
           - inv2 * 0.003968253968253968f));
}

// Wprep layout (fp16): idx = ((s*16 + T)*64 + lane)*8 + e
//   s = 0..3 : Wh for k = s*32 + (lane>>4)*8 + e
//   s = 4..7 : Wl for k = (s-4)*32 + (lane>>4)*8 + e
//   col = T*16 + (lane&15);  W[k][col]: k<64 -> wb[k] (x coeff), k>=64 -> wa[k-64] (x^2 coeff)
__global__ void dpmm_prep(const float* __restrict__ u, const float* __restrict__ v,
                          const float* __restrict__ tau, const float* __restrict__ c,
                          const float* __restrict__ n, const float* __restrict__ B,
                          const float* __restrict__ tau0, const float* __restrict__ c0,
                          const float* __restrict__ n0, const float* __restrict__ B0,
                          float* __restrict__ ws) {
  __shared__ float eb_s[KCL], e1b_s[KCL], elogpi_s[KCL];
  __shared__ double kl_s[KCL];
  const int k = threadIdx.x;            // cluster index (output col)
  _Float16* Wp = (_Float16*)ws;

  float uk = u[k], vk = v[k];
  float dig_sum = digamma_f(uk + vk);
  float eb  = digamma_f(uk) - dig_sum;
  float e1b = digamma_f(vk) - dig_sum;
  eb_s[k] = eb; e1b_s[k] = e1b;
  __syncthreads();
  if (k == 0) {
    float run = 0.0f;
    for (int j = 0; j < KCL; ++j) { elogpi_s[j] = eb_s[j] + run; run += e1b_s[j]; }
  }
  __syncthreads();

  float nk = n[k], ck = c[k], n0k = n0[k], c0k = c0[k];
  float a = 0.5f * nk, a0 = 0.5f * n0k;
  float dga  = digamma_f(a);
  float lga  = lgammaf(a);
  float lga0 = lgammaf(a0);

  const int T = k >> 4, c15 = k & 15;
  float  sumNegLogB = 0.0f, sumElamTau2 = 0.0f;
  double klg = 0.0, knq = 0.0;
  for (int d = 0; d < DDIM; ++d) {
    float Bkd  = B[k * DDIM + d];
    float tkd  = tau[k * DDIM + d];
    float B0kd = B0[k * DDIM + d];
    float t0kd = tau0[k * DDIM + d];
    float Elam = nk / Bkd;
    float wb = Elam * tkd;        // coeff of x   (k-row d)
    float wa = -0.5f * Elam;      // coeff of x^2 (k-row 64+d)
    int   kks[2] = { d, 64 + d };
    float wvs[2] = { wb, wa };
    #pragma unroll
    for (int q = 0; q < 2; ++q) {
      int kk = kks[q]; float wq = wvs[q];
      int ks = kk >> 5, g = (kk >> 3) & 3, e = kk & 7;
      int lanei = g * 16 + c15;
      _Float16 h  = (_Float16)wq;
      _Float16 lo = (_Float16)(wq - (float)h);
      Wp[(( ks      * 16 + T) * 64 + lanei) * 8 + e] = h;
      Wp[(((4 + ks) * 16 + T) * 64 + lanei) * 8 + e] = lo;
    }
    sumNegLogB  -= logf(Bkd);
    sumElamTau2 += Elam * tkd * tkd;
    float b = 0.5f * Bkd, b0 = 0.5f * B0kd;
    klg += (double)((a - a0) * dga - lga + lga0
                    + a0 * (logf(b) - logf(b0)) + a * (b0 - b) / b);
    float dt = tkd - t0kd;
    knq += (double)(Elam * dt * dt);
  }
  float sumEloglam = (float)DDIM * (dga + 0.6931471805599453f) + sumNegLogB;
  ws[OFF_BASE + k] = elogpi_s[k]
      + 0.5f * (sumEloglam - (float)DDIM * 1.8378770664093453f
                - (float)DDIM / ck - sumElamTau2);

  float klb = lgammaf(uk + vk) - lgammaf(uk) - lgammaf(vk)
            - (lgammaf(1.0f + ALPHA_DP) - lgammaf(ALPHA_DP))
            + (uk - 1.0f) * eb + (vk - ALPHA_DP) * e1b;
  float kln = 0.5f * (float)DDIM * (c0k / ck - 1.0f + logf(ck / c0k))
            + 0.5f * c0k * (float)knq;
  kl_s[k] = (double)klb + klg + (double)kln;
  __syncthreads();
  if (k == 0) {
    double tot = 0.0;
    for (int j = 0; j < KCL; ++j) tot += kl_s[j];
    ws[OFF_KL] = (float)tot;
  }
}

__device__ __forceinline__ void split8(const float* v, f16x8& h, f16x8& l) {
  #pragma unroll
  for (int e = 0; e < 8; ++e) {
    _Float16 hh = (_Float16)v[e];
    h[e] = hh;
    l[e] = (_Float16)(v[e] - (float)hh);
  }
}

extern __shared__ _Float16 W_sh[];   // 65536 fp16 = 128 KB

__global__ __launch_bounds__(512) void dpmm_mfma(
    const float* __restrict__ x, const _Float16* __restrict__ Wp,
    const float* __restrict__ base,
    float* __restrict__ pi, float* __restrict__ partial) {
  const int tid  = threadIdx.x;
  const int lane = tid & 63;
  const int w    = tid >> 6;
  const int g    = lane >> 4;          // 16-lane group
  const int c15  = lane & 15;

  // ---- stage W (linear copy: global layout == LDS layout) ----
  {
    const float4* gsrc = (const float4*)Wp;     // 8192 float4
    float4* ldst = (float4*)W_sh;
    #pragma unroll
    for (int it = 0; it < 16; ++it) {
      int idx = it * 512 + tid;
      ldst[idx] = gsrc[idx];
    }
  }

  // ---- build A fragments (hi/lo fp16) from direct x loads ----
  const long row0 = (long)blockIdx.x * ROWS_PER_BLK + (long)w * ROWS_PER_WAVE;
  f16x8 ah[2][4], al[2][4];
  #pragma unroll
  for (int sub = 0; sub < 2; ++sub) {
    const long r = row0 + sub * 16 + c15;       // A-frag row = lane&15
    const float* xr = x + r * DDIM + g * 8;     // features g*8..g*8+7
    float4 A0 = *(const float4*)(xr + 0);
    float4 A1 = *(const float4*)(xr + 4);
    float4 B0 = *(const float4*)(xr + 32);      // features 32+g*8..
    float4 B1 = *(const float4*)(xr + 36);
    float c0[8] = {A0.x,A0.y,A0.z,A0.w,A1.x,A1.y,A1.z,A1.w};
    float c1[8] = {B0.x,B0.y,B0.z,B0.w,B1.x,B1.y,B1.z,B1.w};
    float q0[8], q1[8];
    #pragma unroll
    for (int e = 0; e < 8; ++e) { q0[e] = c0[e]*c0[e]; q1[e] = c1[e]*c1[e]; }
    split8(c0, ah[sub][0], al[sub][0]);   // k 0..31   : x
    split8(c1, ah[sub][1], al[sub][1]);   // k 32..63  : x
    split8(q0, ah[sub][2], al[sub][2]);   // k 64..95  : x^2
    split8(q1, ah[sub][3], al[sub][3]);   // k 96..127 : x^2
  }

  // ---- init acc with base[col] ----
  f32x4 acc[2][16];
  #pragma unroll
  for (int T = 0; T < 16; ++T) {
    float bb = base[T * 16 + c15];
    f32x4 bv = { bb, bb, bb, bb };
    acc[0][T] = bv; acc[1][T] = bv;
  }

  __syncthreads();   // W staged

  // ---- 3-pass split GEMM: AhWh + AhWl + AlWh ----
  #pragma unroll
  for (int pss = 0; pss < 3; ++pss) {
    #pragma unroll
    for (int kk = 0; kk < 4; ++kk) {
      const int s = (pss == 1) ? (4 + kk) : kk;
      const f16x8 aa0 = (pss == 2) ? al[0][kk] : ah[0][kk];
      const f16x8 aa1 = (pss == 2) ? al[1][kk] : ah[1][kk];
      #pragma unroll
      for (int T = 0; T < 16; ++T) {
        f16x8 b = *(const f16x8*)&W_sh[(size_t)((s * 16 + T) * 64 + lane) * 8];
        acc[0][T] = __builtin_amdgcn_mfma_f32_16x16x32_f16(aa0, b, acc[0][T], 0, 0, 0);
        acc[1][T] = __builtin_amdgcn_mfma_f32_16x16x32_f16(aa1, b, acc[1][T], 0, 0, 0);
      }
    }
  }

  // ---- softmax epilogue; C layout: col = T*16 + (lane&15), row = g*4 + j ----
  float wls = 0.0f;
  #pragma unroll
  for (int sub = 0; sub < 2; ++sub) {
    #pragma unroll
    for (int j = 0; j < 4; ++j) {
      float m = acc[sub][0][j];
      #pragma unroll
      for (int T = 1; T < 16; ++T) m = fmaxf(m, acc[sub][T][j]);
      m = fmaxf(m, __shfl_xor(m, 1, 64));
      m = fmaxf(m, __shfl_xor(m, 2, 64));
      m = fmaxf(m, __shfl_xor(m, 4, 64));
      m = fmaxf(m, __shfl_xor(m, 8, 64));
      float ev[16]; float s = 0.0f;
      #pragma unroll
      for (int T = 0; T < 16; ++T) { ev[T] = __expf(acc[sub][T][j] - m); s += ev[T]; }
      s += __shfl_xor(s, 1, 64);
      s += __shfl_xor(s, 2, 64);
      s += __shfl_xor(s, 4, 64);
      s += __shfl_xor(s, 8, 64);
      float rs = 1.0f / s;
      const long r = row0 + sub * 16 + g * 4 + j;
      float* pr = pi + r * KCL + c15;
      #pragma unroll
      for (int T = 0; T < 16; ++T)
        __builtin_nontemporal_store(ev[T] * rs, pr + T * 16);
      wls += m + __logf(s);      // identical across the 16-lane group
    }
  }
  wls += __shfl_xor(wls, 16, 64);
  wls += __shfl_xor(wls, 32, 64);
  if (lane == 0) partial[blockIdx.x * WAVES_PER_BLK + w] = wls;
}

__global__ void dpmm_fin(const float* __restrict__ partial,
                         const float* __restrict__ kl,
                         float* __restrict__ out_elbo) {
  __shared__ double red[256];
  const int t = threadIdx.x;
  double s = 0.0;
  for (int i = t; i < NPART; i += 256) s += (double)partial[i];
  red[t] = s;
  __syncthreads();
  for (int off = 128; off; off >>= 1) {
    if (t < off) red[t] += red[t + off];
    __syncthreads();
  }
  if (t == 0) out_elbo[0] = (float)(red[0] - (double)kl[0]);
}

extern "C" void kernel_launch(void* const* d_in, const int* in_sizes, int n_in,
                              void* d_out, int out_size, void* d_ws, size_t ws_size,
                              hipStream_t stream) {
  const float* x    = (const float*)d_in[0];
  const float* u    = (const float*)d_in[1];
  const float* v    = (const float*)d_in[2];
  const float* tau  = (const float*)d_in[3];
  const float* c    = (const float*)d_in[4];
  const float* n    = (const float*)d_in[5];
  const float* B    = (const float*)d_in[6];
  const float* tau0 = (const float*)d_in[7];
  const float* c0   = (const float*)d_in[8];
  const float* n0   = (const float*)d_in[9];
  const float* B0   = (const float*)d_in[10];

  float* out = (float*)d_out;
  float* ws  = (float*)d_ws;

  (void)hipFuncSetAttribute((const void*)dpmm_mfma,
                            hipFuncAttributeMaxDynamicSharedMemorySize, 131072);

  dpmm_prep<<<1, KCL, 0, stream>>>(u, v, tau, c, n, B, tau0, c0, n0, B0, ws);

  const _Float16* Wp = (const _Float16*)ws;
  const float* base  = ws + OFF_BASE;
  const float* kl    = ws + OFF_KL;
  float* partial     = ws + OFF_PART;

  dpmm_mfma<<<NBLK_MAIN, 512, 131072, stream>>>(x, Wp, base, out, partial);
  dpmm_fin<<<1, 256, 0, stream>>>(partial, kl, out + (size_t)NPTS * KCL);
}

// Round 6
// 228.946 us; speedup vs baseline: 3.5390x; 1.2444x over previous
//
#include <hip/hip_runtime.h>
#include <math.h>

#define NPTS 262144
#define KCL  256
#define DDIM 64
#define ALPHA_DP 1.0f

#define ROWS_PER_WAVE 32
#define WAVES_PER_BLK 8
#define ROWS_PER_BLK  (ROWS_PER_WAVE * WAVES_PER_BLK)   // 256
#define NBLK_MAIN     (NPTS / ROWS_PER_BLK)             // 1024
#define NPART         (NPTS / ROWS_PER_WAVE)            // 8192

// ws float offsets: [0..32768) Wprep (65536 fp16), base, kl, partials
#define OFF_BASE 32768
#define OFF_KL   33024
#define OFF_PART 33025

typedef _Float16 f16x8 __attribute__((ext_vector_type(8)));
typedef float    f32x4 __attribute__((ext_vector_type(4)));

__device__ __forceinline__ float digamma_f(float x) {
  float r = 0.0f;
  while (x < 6.0f) { r -= 1.0f / x; x += 1.0f; }
  float inv  = 1.0f / x;
  float inv2 = inv * inv;
  return r + logf(x) - 0.5f * inv
       - inv2 * (0.083333333333333333f
         - inv2 * (0.008333333333333333f
           - inv2 * 0.003968253968253968f));
}

// Wprep layout (fp16): idx = ((s*16 + T)*64 + lane)*8 + e
//   s = 0..3 : Wh for k-rows s*32 + (lane>>4)*8 + e
//   s = 4..7 : Wl for k-rows (s-4)*32 + (lane>>4)*8 + e
// TRANSPOSED cluster placement: cluster k sits at tile T=(k&15), lane-col c15=(k>>4)
// so in the MFMA C layout each lane owns 16 CONTIGUOUS clusters (k = c15*16 .. +15)
// -> pi stores are 4x dwordx4 per row per lane (full 64B), not 16 scalars.
__global__ void dpmm_prep(const float* __restrict__ u, const float* __restrict__ v,
                          const float* __restrict__ tau, const float* __restrict__ c,
                          const float* __restrict__ n, const float* __restrict__ B,
                          const float* __restrict__ tau0, const float* __restrict__ c0,
                          const float* __restrict__ n0, const float* __restrict__ B0,
                          float* __restrict__ ws) {
  __shared__ float eb_s[KCL], e1b_s[KCL], elogpi_s[KCL];
  __shared__ double kl_s[KCL];
  const int k = threadIdx.x;            // cluster index
  _Float16* Wp = (_Float16*)ws;

  float uk = u[k], vk = v[k];
  float dig_sum = digamma_f(uk + vk);
  float eb  = digamma_f(uk) - dig_sum;
  float e1b = digamma_f(vk) - dig_sum;
  eb_s[k] = eb; e1b_s[k] = e1b;
  __syncthreads();
  if (k == 0) {
    float run = 0.0f;
    for (int j = 0; j < KCL; ++j) { elogpi_s[j] = eb_s[j] + run; run += e1b_s[j]; }
  }
  __syncthreads();

  float nk = n[k], ck = c[k], n0k = n0[k], c0k = c0[k];
  float a = 0.5f * nk, a0 = 0.5f * n0k;
  float dga  = digamma_f(a);
  float lga  = lgammaf(a);
  float lga0 = lgammaf(a0);

  const int T = k & 15, c15 = k >> 4;   // transposed placement
  float  sumNegLogB = 0.0f, sumElamTau2 = 0.0f;
  double klg = 0.0, knq = 0.0;
  for (int d = 0; d < DDIM; ++d) {
    float Bkd  = B[k * DDIM + d];
    float tkd  = tau[k * DDIM + d];
    float B0kd = B0[k * DDIM + d];
    float t0kd = tau0[k * DDIM + d];
    float Elam = nk / Bkd;
    float wb = Elam * tkd;        // coeff of x   (k-row d)
    float wa = -0.5f * Elam;      // coeff of x^2 (k-row 64+d)
    int   kks[2] = { d, 64 + d };
    float wvs[2] = { wb, wa };
    #pragma unroll
    for (int q = 0; q < 2; ++q) {
      int kk = kks[q]; float wq = wvs[q];
      int ks = kk >> 5, g = (kk >> 3) & 3, e = kk & 7;
      int lanei = g * 16 + c15;
      _Float16 h  = (_Float16)wq;
      _Float16 lo = (_Float16)(wq - (float)h);
      Wp[(( ks      * 16 + T) * 64 + lanei) * 8 + e] = h;
      Wp[(((4 + ks) * 16 + T) * 64 + lanei) * 8 + e] = lo;
    }
    sumNegLogB  -= logf(Bkd);
    sumElamTau2 += Elam * tkd * tkd;
    float b = 0.5f * Bkd, b0 = 0.5f * B0kd;
    klg += (double)((a - a0) * dga - lga + lga0
                    + a0 * (logf(b) - logf(b0)) + a * (b0 - b) / b);
    float dt = tkd - t0kd;
    knq += (double)(Elam * dt * dt);
  }
  float sumEloglam = (float)DDIM * (dga + 0.6931471805599453f) + sumNegLogB;
  ws[OFF_BASE + k] = elogpi_s[k]
      + 0.5f * (sumEloglam - (float)DDIM * 1.8378770664093453f
                - (float)DDIM / ck - sumElamTau2);

  float klb = lgammaf(uk + vk) - lgammaf(uk) - lgammaf(vk)
            - (lgammaf(1.0f + ALPHA_DP) - lgammaf(ALPHA_DP))
            + (uk - 1.0f) * eb + (vk - ALPHA_DP) * e1b;
  float kln = 0.5f * (float)DDIM * (c0k / ck - 1.0f + logf(ck / c0k))
            + 0.5f * c0k * (float)knq;
  kl_s[k] = (double)klb + klg + (double)kln;
  __syncthreads();
  if (k == 0) {
    double tot = 0.0;
    for (int j = 0; j < KCL; ++j) tot += kl_s[j];
    ws[OFF_KL] = (float)tot;
  }
}

__device__ __forceinline__ void split8(const float* v, f16x8& h, f16x8& l) {
  #pragma unroll
  for (int e = 0; e < 8; ++e) {
    _Float16 hh = (_Float16)v[e];
    h[e] = hh;
    l[e] = (_Float16)(v[e] - (float)hh);
  }
}

extern __shared__ _Float16 W_sh[];   // 65536 fp16 = 128 KB

__global__ __launch_bounds__(512) void dpmm_mfma(
    const float* __restrict__ x, const _Float16* __restrict__ Wp,
    const float* __restrict__ base,
    float* __restrict__ pi, float* __restrict__ partial) {
  const int tid  = threadIdx.x;
  const int lane = tid & 63;
  const int w    = tid >> 6;
  const int g    = lane >> 4;          // 16-lane group
  const int c15  = lane & 15;

  // ---- issue x loads first (latency hides under W staging) ----
  const long row0 = (long)blockIdx.x * ROWS_PER_BLK + (long)w * ROWS_PER_WAVE;
  float4 xr_[2][4];
  #pragma unroll
  for (int sub = 0; sub < 2; ++sub) {
    const long r = row0 + sub * 16 + c15;       // A-frag row = lane&15
    const float* xr = x + r * DDIM + g * 8;
    xr_[sub][0] = *(const float4*)(xr + 0);
    xr_[sub][1] = *(const float4*)(xr + 4);
    xr_[sub][2] = *(const float4*)(xr + 32);
    xr_[sub][3] = *(const float4*)(xr + 36);
  }

  // ---- stage W (linear copy: global layout == LDS layout) ----
  {
    const float4* gsrc = (const float4*)Wp;     // 8192 float4
    float4* ldst = (float4*)W_sh;
    #pragma unroll
    for (int it = 0; it < 16; ++it) {
      int idx = it * 512 + tid;
      ldst[idx] = gsrc[idx];
    }
  }

  // ---- build A fragments (hi/lo fp16) ----
  f16x8 ah[2][4], al[2][4];
  #pragma unroll
  for (int sub = 0; sub < 2; ++sub) {
    float c0[8] = {xr_[sub][0].x, xr_[sub][0].y, xr_[sub][0].z, xr_[sub][0].w,
                   xr_[sub][1].x, xr_[sub][1].y, xr_[sub][1].z, xr_[sub][1].w};
    float c1[8] = {xr_[sub][2].x, xr_[sub][2].y, xr_[sub][2].z, xr_[sub][2].w,
                   xr_[sub][3].x, xr_[sub][3].y, xr_[sub][3].z, xr_[sub][3].w};
    float q0[8], q1[8];
    #pragma unroll
    for (int e = 0; e < 8; ++e) { q0[e] = c0[e]*c0[e]; q1[e] = c1[e]*c1[e]; }
    split8(c0, ah[sub][0], al[sub][0]);   // k 0..31   : x
    split8(c1, ah[sub][1], al[sub][1]);   // k 32..63  : x
    split8(q0, ah[sub][2], al[sub][2]);   // k 64..95  : x^2
    split8(q1, ah[sub][3], al[sub][3]);   // k 96..127 : x^2
  }

  // ---- init acc with base[cluster]; lane c15 tile T -> cluster c15*16+T ----
  f32x4 acc[2][16];
  #pragma unroll
  for (int T = 0; T < 16; ++T) {
    float bb = base[c15 * 16 + T];
    f32x4 bv = { bb, bb, bb, bb };
    acc[0][T] = bv; acc[1][T] = bv;
  }

  __syncthreads();   // W staged

  // ---- split GEMM, Wh frags reused 4x (AhWh + AlWh), Wl reused 2x (AhWl) ----
  #pragma unroll
  for (int kk = 0; kk < 4; ++kk) {
    #pragma unroll
    for (int T = 0; T < 16; ++T) {
      f16x8 b = *(const f16x8*)&W_sh[(size_t)((kk * 16 + T) * 64 + lane) * 8];
      acc[0][T] = __builtin_amdgcn_mfma_f32_16x16x32_f16(ah[0][kk], b, acc[0][T], 0, 0, 0);
      acc[1][T] = __builtin_amdgcn_mfma_f32_16x16x32_f16(ah[1][kk], b, acc[1][T], 0, 0, 0);
      acc[0][T] = __builtin_amdgcn_mfma_f32_16x16x32_f16(al[0][kk], b, acc[0][T], 0, 0, 0);
      acc[1][T] = __builtin_amdgcn_mfma_f32_16x16x32_f16(al[1][kk], b, acc[1][T], 0, 0, 0);
    }
  }
  #pragma unroll
  for (int kk = 0; kk < 4; ++kk) {
    #pragma unroll
    for (int T = 0; T < 16; ++T) {
      f16x8 b = *(const f16x8*)&W_sh[(size_t)(((4 + kk) * 16 + T) * 64 + lane) * 8];
      acc[0][T] = __builtin_amdgcn_mfma_f32_16x16x32_f16(ah[0][kk], b, acc[0][T], 0, 0, 0);
      acc[1][T] = __builtin_amdgcn_mfma_f32_16x16x32_f16(ah[1][kk], b, acc[1][T], 0, 0, 0);
    }
  }

  // ---- softmax epilogue; C layout: row = g*4+j, lane c15 owns cols c15*16..+15 ----
  float wls = 0.0f;
  #pragma unroll
  for (int sub = 0; sub < 2; ++sub) {
    #pragma unroll
    for (int j = 0; j < 4; ++j) {
      float m = acc[sub][0][j];
      #pragma unroll
      for (int T = 1; T < 16; ++T) m = fmaxf(m, acc[sub][T][j]);
      m = fmaxf(m, __shfl_xor(m, 1, 64));
      m = fmaxf(m, __shfl_xor(m, 2, 64));
      m = fmaxf(m, __shfl_xor(m, 4, 64));
      m = fmaxf(m, __shfl_xor(m, 8, 64));
      float ev[16]; float s = 0.0f;
      #pragma unroll
      for (int T = 0; T < 16; ++T) { ev[T] = __expf(acc[sub][T][j] - m); s += ev[T]; }
      s += __shfl_xor(s, 1, 64);
      s += __shfl_xor(s, 2, 64);
      s += __shfl_xor(s, 4, 64);
      s += __shfl_xor(s, 8, 64);
      float rs = 1.0f / s;
      const long r = row0 + sub * 16 + g * 4 + j;
      float* pr = pi + r * KCL + c15 * 16;       // 16 contiguous cols per lane
      #pragma unroll
      for (int ch = 0; ch < 4; ++ch) {
        f32x4 pv = { ev[4*ch+0] * rs, ev[4*ch+1] * rs,
                     ev[4*ch+2] * rs, ev[4*ch+3] * rs };
        *(f32x4*)(pr + 4 * ch) = pv;             // plain cached store (WRITE_SIZE A/B)
      }
      wls += m + __logf(s);
    }
  }
  wls += __shfl_xor(wls, 16, 64);
  wls += __shfl_xor(wls, 32, 64);
  if (lane == 0) partial[blockIdx.x * WAVES_PER_BLK + w] = wls;
}

__global__ void dpmm_fin(const float* __restrict__ partial,
                         const float* __restrict__ kl,
                         float* __restrict__ out_elbo) {
  __shared__ double red[256];
  const int t = threadIdx.x;
  double s = 0.0;
  for (int i = t; i < NPART; i += 256) s += (double)partial[i];
  red[t] = s;
  __syncthreads();
  for (int off = 128; off; off >>= 1) {
    if (t < off) red[t] += red[t + off];
    __syncthreads();
  }
  if (t == 0) out_elbo[0] = (float)(red[0] - (double)kl[0]);
}

extern "C" void kernel_launch(void* const* d_in, const int* in_sizes, int n_in,
                              void* d_out, int out_size, void* d_ws, size_t ws_size,
                              hipStream_t stream) {
  const float* x    = (const float*)d_in[0];
  const float* u    = (const float*)d_in[1];
  const float* v    = (const float*)d_in[2];
  const float* tau  = (const float*)d_in[3];
  const float* c    = (const float*)d_in[4];
  const float* n    = (const float*)d_in[5];
  const float* B    = (const float*)d_in[6];
  const float* tau0 = (const float*)d_in[7];
  const float* c0   = (const float*)d_in[8];
  const float* n0   = (const float*)d_in[9];
  const float* B0   = (const float*)d_in[10];

  float* out = (float*)d_out;
  float* ws  = (float*)d_ws;

  (void)hipFuncSetAttribute((const void*)dpmm_mfma,
                            hipFuncAttributeMaxDynamicSharedMemorySize, 131072);

  dpmm_prep<<<1, KCL, 0, stream>>>(u, v, tau, c, n, B, tau0, c0, n0, B0, ws);

  const _Float16* Wp = (const _Float16*)ws;
  const float* base  = ws + OFF_BASE;
  const float* kl    = ws + OFF_KL;
  float* partial     = ws + OFF_PART;

  dpmm_mfma<<<NBLK_MAIN, 512, 131072, stream>>>(x, Wp, base, out, partial);
  dpmm_fin<<<1, 256, 0, stream>>>(partial, kl, out + (size_t)NPTS * KCL);
}